// Round 8
// baseline (391.042 us; speedup 1.0000x reference)
//
#include <hip/hip_runtime.h>
#include <hip/hip_bf16.h>

typedef __bf16 bf16_t;
typedef bf16_t bf16x8 __attribute__((ext_vector_type(8)));
typedef float f32x4 __attribute__((ext_vector_type(4)));
typedef float f32x2 __attribute__((ext_vector_type(2)));

#define EPS_BN 1e-5f
#define EPS_LN 1e-5f
#define SLOTS 32
#define WSCALE 32767.f
#define WINV (1.f / 32767.f)
#define RNODES 448          // nodes per bucket (slot tile = 448*32*4 = 56KB LDS)
#define OV_CAP 16384
#define OVA_CAP 65536

__device__ __forceinline__ float blo(unsigned u) { return __uint_as_float(u << 16); }
__device__ __forceinline__ float bhi(unsigned u) { return __uint_as_float(u & 0xFFFF0000u); }
__device__ __forceinline__ f32x2 f8lo(unsigned u) { return __builtin_amdgcn_cvt_pk_f32_fp8((int)u, false); }
__device__ __forceinline__ f32x2 f8hi(unsigned u) { return __builtin_amdgcn_cvt_pk_f32_fp8((int)u, true); }

#define ACC8(U, W) do { \
    f32x2 Wv = (f32x2){(W), (W)}; \
    acc[0] += Wv * f8lo((U).x); acc[1] += Wv * f8hi((U).x); \
    acc[2] += Wv * f8lo((U).y); acc[3] += Wv * f8hi((U).y); \
    acc[4] += Wv * f8lo((U).z); acc[5] += Wv * f8hi((U).z); \
    acc[6] += Wv * f8lo((U).w); acc[7] += Wv * f8hi((U).w); } while (0)

// ---------------- prep: zero cursors + convert 4x W[i][o] fp32 -> WT[o*136+i] bf16 ----------------

__global__ void prepK(const float* __restrict__ W0, const float* __restrict__ W1,
                      const float* __restrict__ W2, const float* __restrict__ W3,
                      bf16_t* __restrict__ WT, int* __restrict__ bCnt,
                      int* __restrict__ ovCnt, int* __restrict__ ovACnt) {
    int flat = blockIdx.x * 256 + threadIdx.x;
    if (flat == 0) { *ovCnt = 0; *ovACnt = 0; }
    if (flat < 4096) bCnt[flat] = 0;
    if (flat < 65536) {
        int which = flat >> 14, r = flat & 16383;
        const float* W = (which == 0) ? W0 : (which == 1) ? W1 : (which == 2) ? W2 : W3;
        int i = r >> 7, o = r & 127;
        WT[which * 128 * 136 + o * 136 + i] = (bf16_t)W[r];
    }
}

// ---------------- adjacency build, phase A: radix-bin edges by dst/RNODES ----------------
// Round-2 proven config: 4096 edges/block. Per-edge positions via LDS atomics; ONE
// device-scope atomic per bucket per block (88K total).

__global__ __launch_bounds__(256) void binK(
    const int* __restrict__ ei, const float* __restrict__ ea,
    uint2* __restrict__ bbuf, int* __restrict__ bCnt,
    uint2* __restrict__ ovA, int* __restrict__ ovACnt,
    int E, int cap, int nbuck)
{
    __shared__ int lcnt[256];
    __shared__ int gbase[256];
    int tid = threadIdx.x;
    if (tid < nbuck) lcnt[tid] = 0;
    __syncthreads();

    int e0 = blockIdx.x * 4096 + tid;
    int d[16]; unsigned pk[16]; int p[16];
#pragma unroll
    for (int k = 0; k < 16; ++k) {
        int e = e0 + k * 256;
        p[k] = -1;
        if (e < E) {
            d[k] = ei[E + e];                    // edge_index[1][e]
            int s = ei[e];                       // edge_index[0][e]
            unsigned wq = __float2uint_rn(ea[e] * WSCALE);
            pk[k] = ((unsigned)s << 15) | wq;
            p[k] = atomicAdd(&lcnt[(unsigned)d[k] / RNODES], 1);
        }
    }
    __syncthreads();
    if (tid < nbuck) gbase[tid] = atomicAdd(&bCnt[tid * 16], lcnt[tid]);
    __syncthreads();
#pragma unroll
    for (int k = 0; k < 16; ++k) {
        if (p[k] >= 0) {
            int b = (unsigned)d[k] / RNODES;
            int idx = gbase[b] + p[k];
            if (idx < cap) {
                bbuf[(size_t)b * cap + idx] = make_uint2((unsigned)d[k], pk[k]);
            } else {
                int o = atomicAdd(ovACnt, 1);    // statistically-never (cap = mean+4096)
                if (o < OVA_CAP) ovA[o] = make_uint2((unsigned)d[k], pk[k]);
            }
        }
    }
}

// ---------------- adjacency build, phase B: LDS-resident slot fill, one block per bucket ----------

__global__ __launch_bounds__(256) void buildK(
    const uint2* __restrict__ bbuf, const int* __restrict__ bCnt,
    const uint2* __restrict__ ovA, const int* __restrict__ ovACnt,
    unsigned* __restrict__ slots, int* __restrict__ cnt, float* __restrict__ dinv,
    uint2* __restrict__ ov, int* __restrict__ ovCnt,
    int cap, int n)
{
    __shared__ unsigned slotsL[RNODES * 32];   // 56KB
    __shared__ int cntL[RNODES];
    __shared__ float wsumL[RNODES];
    int tid = threadIdx.x;
    int base = blockIdx.x * RNODES;

    for (int j = tid; j < RNODES; j += 256) { cntL[j] = 0; wsumL[j] = 0.f; }
    __syncthreads();

    int nb = min(bCnt[blockIdx.x * 16], cap);
    const uint2* buf = bbuf + (size_t)blockIdx.x * cap;
    for (int i = tid; i < nb; i += 256) {
        uint2 u = buf[i];
        int local = (int)u.x - base;
        int pos = atomicAdd(&cntL[local], 1);
        atomicAdd(&wsumL[local], (float)(u.y & 32767u) * WINV);
        if (pos < SLOTS) {
            slotsL[local * 32 + pos] = u.y;
        } else {
            int o = atomicAdd(ovCnt, 1);
            if (o < OV_CAP) ov[o] = u;
        }
    }
    // bucket-overflow edges from phase A (rare): fold into this range's structure
    int no = min(*ovACnt, OVA_CAP);
    for (int k = tid; k < no; k += 256) {
        uint2 u = ovA[k];
        int local = (int)u.x - base;
        if (local >= 0 && local < RNODES) {
            int pos = atomicAdd(&cntL[local], 1);
            atomicAdd(&wsumL[local], (float)(u.y & 32767u) * WINV);
            if (pos < SLOTS) {
                slotsL[local * 32 + pos] = u.y;
            } else {
                int o = atomicAdd(ovCnt, 1);
                if (o < OV_CAP) ov[o] = u;
            }
        }
    }
    __syncthreads();

    // pad slots to mult-of-8 with (self, w=0); cnt; dinv = rsqrt(1 + sum w)
    for (int j = tid; j < RNODES; j += 256) {
        int node = base + j;
        if (node < n) {
            int c = cntL[j];
            int cm = min(c, SLOTS);
            int c8 = (cm + 7) & ~7;
            for (int k2 = cm; k2 < c8; ++k2) slotsL[j * 32 + k2] = (unsigned)node << 15;
            cnt[node] = c;
            dinv[node] = rsqrtf(fmaxf(1.f + wsumL[j], 1e-12f));
        }
    }
    __syncthreads();

    int vnodes = min(n - base, RNODES);
    if (vnodes <= 0) return;
    const uint4* sl4 = (const uint4*)slotsL;
    uint4* sg4 = (uint4*)(slots + ((size_t)base << 5));
    int lim = vnodes * 8;                      // uint4s = nodes*32/4
    for (int i = tid; i < lim; i += 256) sg4[i] = sl4[i];
}

// ---------------- GEMM: out[r][j] = epilogue( sum_k A[r][k]*W[k][j] ) ----------------
// MODE 0: BN(acc + colBias) then ReLU -> bf16   (input preprocess, A fp32)
// MODE 1: acc * dinv[row] -> fp8 e4m3, stored SPLIT: plane h = cols [64h..64h+63]
//         contiguous ([2][N][64B]) so the aggregation halves read disjoint planes.

template <int MODE, typename AT>
__global__ __launch_bounds__(256) void gemm128K(
    const AT* __restrict__ A, const bf16_t* __restrict__ WT,
    bf16_t* __restrict__ outb, unsigned* __restrict__ out8,
    const float* __restrict__ colBias,
    const float* __restrict__ bnMean, const float* __restrict__ bnVar,
    const float* __restrict__ bnG, const float* __restrict__ bnB,
    const float* __restrict__ dinv, int nrows)
{
    __shared__ __align__(16) bf16_t Bs[128 * 136];   // 34816 B
    int tid = threadIdx.x;
    int rb = blockIdx.x * 64;

    {
        const uint4* src = (const uint4*)WT;
        uint4* dst = (uint4*)Bs;
        if (MODE == 1) {
            for (int i = tid; i < 128 * 17; i += 256) {
                int row = i / 17, k = i - row * 17;
                int so = ((row & 15) << 3) | (row >> 4);
                dst[row * 17 + k] = src[so * 17 + k];
            }
        } else {
            for (int i = tid; i < 128 * 17; i += 256) dst[i] = src[i];
        }
    }

    int lane = tid & 63;
    int wid = tid >> 6;
    int m = lane & 15, q = lane >> 4;
    int myRow = rb + wid * 16 + m;
    int rowL = min(myRow, nrows - 1);

    bf16x8 af[4];
    if constexpr (sizeof(AT) == 4) {
#pragma unroll
        for (int kk = 0; kk < 4; ++kk) {
            float4 v0 = ((const float4*)A)[rowL * 32 + q * 2 + kk * 8];
            float4 v1 = ((const float4*)A)[rowL * 32 + q * 2 + kk * 8 + 1];
            bf16x8 w8;
            w8[0] = (bf16_t)v0.x; w8[1] = (bf16_t)v0.y; w8[2] = (bf16_t)v0.z; w8[3] = (bf16_t)v0.w;
            w8[4] = (bf16_t)v1.x; w8[5] = (bf16_t)v1.y; w8[6] = (bf16_t)v1.z; w8[7] = (bf16_t)v1.w;
            af[kk] = w8;
        }
    } else {
#pragma unroll
        for (int kk = 0; kk < 4; ++kk)
            af[kk] = ((const bf16x8*)A)[rowL * 16 + q + kk * 4];
    }

    __syncthreads();

    f32x4 acc[8];
#pragma unroll
    for (int c = 0; c < 8; ++c) acc[c] = (f32x4){0.f, 0.f, 0.f, 0.f};

#pragma unroll
    for (int kk = 0; kk < 4; ++kk) {
#pragma unroll
        for (int c = 0; c < 8; ++c) {
            bf16x8 bfr = *(const bf16x8*)&Bs[(c * 16 + m) * 136 + q * 8 + kk * 32];
            acc[c] = __builtin_amdgcn_mfma_f32_16x16x32_bf16(af[kk], bfr, acc[c], 0, 0, 0);
        }
    }

    int r0 = rb + wid * 16 + q * 4;
    if (MODE == 1) {
        float dv[4];
#pragma unroll
        for (int i = 0; i < 4; ++i) dv[i] = (r0 + i < nrows) ? dinv[r0 + i] : 0.f;
        // lane m covers actual cols m*8..m*8+7 (B col-permuted); plane = m>>3
        size_t pbase = (size_t)(m >> 3) * ((size_t)nrows << 3);
#pragma unroll
        for (int i = 0; i < 4; ++i) {
            int r = r0 + i;
            if (r < nrows) {
                float v0 = acc[0][i] * dv[i], v1 = acc[1][i] * dv[i];
                float v2 = acc[2][i] * dv[i], v3 = acc[3][i] * dv[i];
                float v4 = acc[4][i] * dv[i], v5 = acc[5][i] * dv[i];
                float v6 = acc[6][i] * dv[i], v7 = acc[7][i] * dv[i];
                int lo = __builtin_amdgcn_cvt_pk_fp8_f32(v0, v1, 0, false);
                lo = __builtin_amdgcn_cvt_pk_fp8_f32(v2, v3, lo, true);
                int hi = __builtin_amdgcn_cvt_pk_fp8_f32(v4, v5, 0, false);
                hi = __builtin_amdgcn_cvt_pk_fp8_f32(v6, v7, hi, true);
                ((uint2*)out8)[pbase + (r << 3) + (m & 7)] = make_uint2((unsigned)lo, (unsigned)hi);
            }
        }
    } else {
#pragma unroll
        for (int c = 0; c < 8; ++c) {
            int j = c * 16 + m;
            float cb = colBias[j];
            float rs = rsqrtf(bnVar[j] + EPS_BN);
            float scale = bnG[j] * rs;
            float shift = bnB[j] - bnMean[j] * scale;
#pragma unroll
            for (int i = 0; i < 4; ++i) {
                int r = r0 + i;
                if (r < nrows) {
                    float v = (acc[c][i] + cb) * scale + shift;
                    outb[r * 128 + j] = (bf16_t)fmaxf(v, 0.f);
                }
            }
        }
    }
}

// ---------------- aggregation: split-plane halves with XCD-affinity ----------------
// The fp8 table is stored as two contiguous 6.4MB planes (cols 0-63 / 64-127). Each
// node is handled by two blocks, one per plane, mapped to disjoint XCD sets via the
// round-robin dispatch heuristic (bit2 of blockIdx&7 picks the plane). Each XCD L2
// then streams at most its own plane (6.4MB) instead of the full 12.8MB table.
// Round-7's row-interleaved split FAILED (FETCH 1.8x: half-reads still missed on and
// pulled full-row lines); contiguous planes make the footprints physically disjoint.
// Worst case (heuristic fails): each L2 streams both planes = status quo, neutral.
// Inner loop keeps the round-2 dynamics: dynamic trip count, 8 slots/iter, VGPR ~32.

template <int RELU, int RES>
__global__ __launch_bounds__(256) void aggSK(
    const uint4* __restrict__ ts16, const unsigned* __restrict__ slots,
    const int* __restrict__ cnt, const float* __restrict__ dinv,
    const float4* __restrict__ bias, const uint4* __restrict__ residual,
    uint4* __restrict__ out,
    const uint2* __restrict__ ov, const int* __restrict__ ovCnt, int n)
{
    int tid = threadIdx.x;
    int b = blockIdx.x;
    int p = (b >> 2) & 1;                    // bit2 of (b&7): XCDs 0-3 -> plane 0, 4-7 -> plane 1
    int g = ((b >> 3) << 2) | (b & 3);       // node group, each covered once per plane
    int node = g * 8 + (tid >> 5);
    int hl = tid & 31;
    int hb = tid & 32;
    if (node >= n) return;
    int slot = hl >> 2;                      // 8 slot lanes
    int fc = hl & 3;                         // 4 chunk lanes (16B each) within the 64B half
    size_t pb = (size_t)p * ((size_t)n << 2);  // plane base, uint4 units

    int c8 = (min(cnt[node], SLOTS) + 7) & ~7;
    unsigned my = slots[(node << 5) | hl];
    float myw = (float)(my & 32767u) * WINV;
    int myoff = (int)(my >> 15) << 2;        // uint4 units within plane: src*4

    f32x2 acc[8];
#pragma unroll
    for (int k = 0; k < 8; ++k) acc[k] = (f32x2){0.f, 0.f};

    // self-loop row folded into slot-1 lanes (weight 1), overlaps the gather loop
    if (slot == 1) {
        uint4 su = ts16[pb + (node << 2) + fc];
        acc[0] += f8lo(su.x); acc[1] += f8hi(su.x);
        acc[2] += f8lo(su.y); acc[3] += f8hi(su.y);
        acc[4] += f8lo(su.z); acc[5] += f8hi(su.z);
        acc[6] += f8lo(su.w); acc[7] += f8hi(su.w);
    }

    for (int j = 0; j < c8; j += 8) {
        int s0 = hb + j + slot;
        int o0 = __shfl(myoff, s0);
        float w0 = __shfl(myw, s0);
        uint4 u0 = ts16[pb + o0 + fc];
        ACC8(u0, w0);
    }

    // overflow edges (rare): slot-0 lanes only, so reduction counts them once
    int no = min(*ovCnt, OV_CAP);
    for (int k = 0; k < no; ++k) {
        uint2 o = ov[k];
        if ((int)o.x == node && slot == 0) {
            uint4 u = ts16[pb + ((int)(o.y >> 15) << 2) + fc];
            float w = (float)(o.y & 32767u) * WINV;
            ACC8(u, w);
        }
    }

    // reduce across the 8 slot lanes (hl bits 2..4)
#pragma unroll
    for (int k = 0; k < 8; ++k) {
        f32x2 t;
        t.x = __shfl_xor(acc[k].x, 4);  t.y = __shfl_xor(acc[k].y, 4);  acc[k] += t;
        t.x = __shfl_xor(acc[k].x, 8);  t.y = __shfl_xor(acc[k].y, 8);  acc[k] += t;
        t.x = __shfl_xor(acc[k].x, 16); t.y = __shfl_xor(acc[k].y, 16); acc[k] += t;
    }

    if (slot == 0) {   // lanes hl<4 hold global chunk gc; epilogue + write
        int gc = (p << 2) | fc;              // global 16B chunk 0..7
        float di = dinv[node];
        float r[16];
#pragma unroll
        for (int k = 0; k < 8; ++k) {
            float4 bb = bias[gc * 4 + (k >> 1)];
            float b0 = (k & 1) ? bb.z : bb.x;
            float b1 = (k & 1) ? bb.w : bb.y;
            r[2 * k]     = acc[k].x * di + b0;
            r[2 * k + 1] = acc[k].y * di + b1;
        }
        if (RES) {
            uint4 q0 = residual[(node << 4) + gc * 2];
            uint4 q1 = residual[(node << 4) + gc * 2 + 1];
            r[0] += blo(q0.x);  r[1] += bhi(q0.x);
            r[2] += blo(q0.y);  r[3] += bhi(q0.y);
            r[4] += blo(q0.z);  r[5] += bhi(q0.z);
            r[6] += blo(q0.w);  r[7] += bhi(q0.w);
            r[8] += blo(q1.x);  r[9] += bhi(q1.x);
            r[10] += blo(q1.y); r[11] += bhi(q1.y);
            r[12] += blo(q1.z); r[13] += bhi(q1.z);
            r[14] += blo(q1.w); r[15] += bhi(q1.w);
        }
        if (RELU) {
#pragma unroll
            for (int k = 0; k < 16; ++k) r[k] = fmaxf(r[k], 0.f);
        }
        bf16x8 o0, o1;
#pragma unroll
        for (int k = 0; k < 8; ++k) { o0[k] = (bf16_t)r[k]; o1[k] = (bf16_t)r[8 + k]; }
        out[(node << 4) + gc * 2]     = *(uint4*)&o0;
        out[(node << 4) + gc * 2 + 1] = *(uint4*)&o1;
    }
}

// ---------------- classifier: z = h@Wc1 + bc1; LN; ReLU; out = z@Wc2 + bc2 ----------------

__global__ __launch_bounds__(256) void classifierK(
    const bf16_t* __restrict__ A, const bf16_t* __restrict__ WT,
    const float* __restrict__ bc1, const float* __restrict__ g,
    const float* __restrict__ b, const float* __restrict__ Wc2,
    const float* __restrict__ bc2, float* __restrict__ out, int nrows)
{
    __shared__ __align__(16) bf16_t Bs[128 * 136];
    __shared__ float sB[128], sG[128], sLb[128], sW2[384];
    int tid = threadIdx.x;
    int rb = blockIdx.x * 64;

    {
        const uint4* src = (const uint4*)WT;
        uint4* dst = (uint4*)Bs;
        for (int i = tid; i < 128 * 17; i += 256) dst[i] = src[i];
    }
    if (tid < 128) { sB[tid] = bc1[tid]; sG[tid] = g[tid]; sLb[tid] = b[tid]; }
    for (int i = tid; i < 384; i += 256) sW2[i] = Wc2[i];

    int lane = tid & 63;
    int wid = tid >> 6;
    int m = lane & 15, q = lane >> 4;
    int rowL = min(rb + wid * 16 + m, nrows - 1);

    bf16x8 af[4];
#pragma unroll
    for (int kk = 0; kk < 4; ++kk)
        af[kk] = ((const bf16x8*)A)[rowL * 16 + q + kk * 4];

    __syncthreads();

    f32x4 acc[8];
#pragma unroll
    for (int c = 0; c < 8; ++c) acc[c] = (f32x4){0.f, 0.f, 0.f, 0.f};
#pragma unroll
    for (int kk = 0; kk < 4; ++kk) {
#pragma unroll
        for (int c = 0; c < 8; ++c) {
            bf16x8 bfr = *(const bf16x8*)&Bs[(c * 16 + m) * 136 + q * 8 + kk * 32];
            acc[c] = __builtin_amdgcn_mfma_f32_16x16x32_bf16(af[kk], bfr, acc[c], 0, 0, 0);
        }
    }

    int r0 = rb + wid * 16 + q * 4;
#pragma unroll
    for (int i = 0; i < 4; ++i) {
        float s1 = 0.f, s2 = 0.f;
#pragma unroll
        for (int c = 0; c < 8; ++c) {
            float z = acc[c][i] + sB[c * 16 + m];
            acc[c][i] = z;
            s1 += z; s2 += z * z;
        }
#pragma unroll
        for (int off = 1; off < 16; off <<= 1) {
            s1 += __shfl_xor(s1, off);
            s2 += __shfl_xor(s2, off);
        }
        float mu = s1 * (1.f / 128.f);
        float var = s2 * (1.f / 128.f) - mu * mu;
        float rstd = rsqrtf(var + EPS_LN);
        float p0 = 0.f, p1 = 0.f, p2 = 0.f;
#pragma unroll
        for (int c = 0; c < 8; ++c) {
            int j = c * 16 + m;
            float zn = (acc[c][i] - mu) * rstd * sG[j] + sLb[j];
            zn = fmaxf(zn, 0.f);
            p0 += zn * sW2[j * 3 + 0];
            p1 += zn * sW2[j * 3 + 1];
            p2 += zn * sW2[j * 3 + 2];
        }
#pragma unroll
        for (int off = 1; off < 16; off <<= 1) {
            p0 += __shfl_xor(p0, off);
            p1 += __shfl_xor(p1, off);
            p2 += __shfl_xor(p2, off);
        }
        int r = r0 + i;
        if (m == 0 && r < nrows) {
            out[r * 3 + 0] = p0 + bc2[0];
            out[r * 3 + 1] = p1 + bc2[1];
            out[r * 3 + 2] = p2 + bc2[2];
        }
    }
}

// ---------------- launch ----------------

extern "C" void kernel_launch(void* const* d_in, const int* in_sizes, int n_in,
                              void* d_out, int out_size, void* d_ws, size_t ws_size,
                              hipStream_t stream) {
    const float* x      = (const float*)d_in[0];
    const int*   ei     = (const int*)d_in[1];
    const float* ea     = (const float*)d_in[2];
    const float* W_pre  = (const float*)d_in[3];
    const float* b_pre  = (const float*)d_in[4];
    const float* bn_g   = (const float*)d_in[5];
    const float* bn_b   = (const float*)d_in[6];
    const float* bn_m   = (const float*)d_in[7];
    const float* bn_v   = (const float*)d_in[8];
    const float* W1     = (const float*)d_in[9];
    const float* b1     = (const float*)d_in[10];
    const float* W2     = (const float*)d_in[11];
    const float* b2     = (const float*)d_in[12];
    const float* Wc1    = (const float*)d_in[13];
    const float* bc1    = (const float*)d_in[14];
    const float* ln_g   = (const float*)d_in[15];
    const float* ln_b   = (const float*)d_in[16];
    const float* Wc2    = (const float*)d_in[17];
    const float* bc2    = (const float*)d_in[18];
    float* outp = (float*)d_out;

    const int N = in_sizes[0] / 128;
    const int E = in_sizes[2];

    char* p = (char*)d_ws;
    auto alloc = [&](size_t bytes) -> void* {
        void* r = (void*)p;
        p += (bytes + 255) & ~(size_t)255;
        return r;
    };
    bf16_t*   h0    = (bf16_t*)alloc((size_t)N * 128 * 2);
    bf16_t*   bufB  = (bf16_t*)alloc((size_t)N * 128 * 2);
    unsigned* ts8   = (unsigned*)alloc((size_t)N * 128);
    float*    dinv  = (float*)alloc((size_t)N * 4);
    int*      cnt   = (int*)alloc((size_t)N * 4);
    int*      ovCnt = (int*)alloc(256);
    int*      ovACnt= (int*)alloc(256);
    uint2*    ov    = (uint2*)alloc((size_t)OV_CAP * 8);
    uint2*    ovA   = (uint2*)alloc((size_t)OVA_CAP * 8);
    unsigned* slots = (unsigned*)alloc((size_t)N * SLOTS * 4);
    bf16_t*   WT    = (bf16_t*)alloc((size_t)4 * 128 * 136 * 2);
    int       nbuck = (N + RNODES - 1) / RNODES;      // 224 for N=100000
    int       cap   = E / nbuck + 4096;
    uint2*    bbuf  = (uint2*)alloc((size_t)nbuck * cap * 8);
    int*      bCnt  = (int*)alloc(4096 * 4);

    bf16_t* WT_pre = WT + 0 * 128 * 136;
    bf16_t* WT_1   = WT + 1 * 128 * 136;
    bf16_t* WT_2   = WT + 2 * 128 * 136;
    bf16_t* WT_c1  = WT + 3 * 128 * 136;

    int gG = (N + 63) / 64;
    int nGrp = (N + 7) / 8;
    int gAgg = ((nGrp + 3) / 4) * 8;       // 2 planes x nGrp, XCD-affine encoding
    int gP = 65536 / 256;
    int gBin = (E + 4095) / 4096;

    prepK<<<gP, 256, 0, stream>>>(W_pre, W1, W2, Wc1, WT, bCnt, ovCnt, ovACnt);
    binK<<<gBin, 256, 0, stream>>>(ei, ea, bbuf, bCnt, ovA, ovACnt, E, cap, nbuck);
    buildK<<<nbuck, 256, 0, stream>>>(bbuf, bCnt, ovA, ovACnt, slots, cnt, dinv, ov, ovCnt, cap, N);

    // h0 = relu(bn(x@W_pre + b_pre))
    gemm128K<0, float><<<gG, 256, 0, stream>>>(x, WT_pre, h0, nullptr, b_pre, bn_m, bn_v, bn_g, bn_b, nullptr, N);
    // conv1: ts8 = fp8(dinv * (h0@W1)), split planes
    gemm128K<1, bf16_t><<<gG, 256, 0, stream>>>(h0, WT_1, nullptr, ts8, nullptr, nullptr, nullptr, nullptr, nullptr, dinv, N);
    aggSK<1, 0><<<gAgg, 256, 0, stream>>>((const uint4*)ts8, slots, cnt, dinv, (const float4*)b1,
                                          nullptr, (uint4*)bufB, ov, ovCnt, N);
    // conv2 (+residual h0)
    gemm128K<1, bf16_t><<<gG, 256, 0, stream>>>(bufB, WT_2, nullptr, ts8, nullptr, nullptr, nullptr, nullptr, nullptr, dinv, N);
    aggSK<0, 1><<<gAgg, 256, 0, stream>>>((const uint4*)ts8, slots, cnt, dinv, (const float4*)b2,
                                          (const uint4*)h0, (uint4*)bufB, ov, ovCnt, N);
    // classifier: out = relu(LN(h@Wc1 + bc1)) @ Wc2 + bc2
    classifierK<<<gG, 256, 0, stream>>>(bufB, WT_c1, bc1, ln_g, ln_b, Wc2, bc2, outp, N);
}

// Round 9
// 314.870 us; speedup vs baseline: 1.2419x; 1.2419x over previous
//
#include <hip/hip_runtime.h>
#include <hip/hip_bf16.h>

typedef __bf16 bf16_t;
typedef bf16_t bf16x8 __attribute__((ext_vector_type(8)));
typedef float f32x4 __attribute__((ext_vector_type(4)));
typedef float f32x2 __attribute__((ext_vector_type(2)));

#define EPS_BN 1e-5f
#define EPS_LN 1e-5f
#define SLOTS 32
#define WSCALE 32767.f
#define WINV (1.f / 32767.f)
#define RNODES 448          // nodes per bucket (slot tile = 448*32*4 = 56KB LDS)
#define OV_CAP 16384
#define OVA_CAP 65536

__device__ __forceinline__ float blo(unsigned u) { return __uint_as_float(u << 16); }
__device__ __forceinline__ float bhi(unsigned u) { return __uint_as_float(u & 0xFFFF0000u); }
__device__ __forceinline__ f32x2 f8lo(unsigned u) { return __builtin_amdgcn_cvt_pk_f32_fp8((int)u, false); }
__device__ __forceinline__ f32x2 f8hi(unsigned u) { return __builtin_amdgcn_cvt_pk_f32_fp8((int)u, true); }

#define ACC8(U, W) do { \
    f32x2 Wv = (f32x2){(W), (W)}; \
    acc[0] += Wv * f8lo((U).x); acc[1] += Wv * f8hi((U).x); \
    acc[2] += Wv * f8lo((U).y); acc[3] += Wv * f8hi((U).y); \
    acc[4] += Wv * f8lo((U).z); acc[5] += Wv * f8hi((U).z); \
    acc[6] += Wv * f8lo((U).w); acc[7] += Wv * f8hi((U).w); } while (0)

// ---------------- prep: zero cursors + convert 4x W[i][o] fp32 -> WT[o*136+i] bf16 ----------------

__global__ void prepK(const float* __restrict__ W0, const float* __restrict__ W1,
                      const float* __restrict__ W2, const float* __restrict__ W3,
                      bf16_t* __restrict__ WT, int* __restrict__ bCnt,
                      int* __restrict__ ovCnt, int* __restrict__ ovACnt) {
    int flat = blockIdx.x * 256 + threadIdx.x;
    if (flat == 0) { *ovCnt = 0; *ovACnt = 0; }
    if (flat < 4096) bCnt[flat] = 0;
    if (flat < 65536) {
        int which = flat >> 14, r = flat & 16383;
        const float* W = (which == 0) ? W0 : (which == 1) ? W1 : (which == 2) ? W2 : W3;
        int i = r >> 7, o = r & 127;
        WT[which * 128 * 136 + o * 136 + i] = (bf16_t)W[r];
    }
}

// ---------------- adjacency build, phase A: radix-bin edges by dst/RNODES ----------------
// Round-2 proven config: 4096 edges/block. Per-edge positions via LDS atomics; ONE
// device-scope atomic per bucket per block (88K total).

__global__ __launch_bounds__(256) void binK(
    const int* __restrict__ ei, const float* __restrict__ ea,
    uint2* __restrict__ bbuf, int* __restrict__ bCnt,
    uint2* __restrict__ ovA, int* __restrict__ ovACnt,
    int E, int cap, int nbuck)
{
    __shared__ int lcnt[256];
    __shared__ int gbase[256];
    int tid = threadIdx.x;
    if (tid < nbuck) lcnt[tid] = 0;
    __syncthreads();

    int e0 = blockIdx.x * 4096 + tid;
    int d[16]; unsigned pk[16]; int p[16];
#pragma unroll
    for (int k = 0; k < 16; ++k) {
        int e = e0 + k * 256;
        p[k] = -1;
        if (e < E) {
            d[k] = ei[E + e];                    // edge_index[1][e]
            int s = ei[e];                       // edge_index[0][e]
            unsigned wq = __float2uint_rn(ea[e] * WSCALE);
            pk[k] = ((unsigned)s << 15) | wq;
            p[k] = atomicAdd(&lcnt[(unsigned)d[k] / RNODES], 1);
        }
    }
    __syncthreads();
    if (tid < nbuck) gbase[tid] = atomicAdd(&bCnt[tid * 16], lcnt[tid]);
    __syncthreads();
#pragma unroll
    for (int k = 0; k < 16; ++k) {
        if (p[k] >= 0) {
            int b = (unsigned)d[k] / RNODES;
            int idx = gbase[b] + p[k];
            if (idx < cap) {
                bbuf[(size_t)b * cap + idx] = make_uint2((unsigned)d[k], pk[k]);
            } else {
                int o = atomicAdd(ovACnt, 1);    // statistically-never (cap = mean+4096)
                if (o < OVA_CAP) ovA[o] = make_uint2((unsigned)d[k], pk[k]);
            }
        }
    }
}

// ---------------- adjacency build, phase B: LDS-resident slot fill, one block per bucket ----------

__global__ __launch_bounds__(256) void buildK(
    const uint2* __restrict__ bbuf, const int* __restrict__ bCnt,
    const uint2* __restrict__ ovA, const int* __restrict__ ovACnt,
    unsigned* __restrict__ slots, int* __restrict__ cnt, float* __restrict__ dinv,
    uint2* __restrict__ ov, int* __restrict__ ovCnt,
    int cap, int n)
{
    __shared__ unsigned slotsL[RNODES * 32];   // 56KB
    __shared__ int cntL[RNODES];
    __shared__ float wsumL[RNODES];
    int tid = threadIdx.x;
    int base = blockIdx.x * RNODES;

    for (int j = tid; j < RNODES; j += 256) { cntL[j] = 0; wsumL[j] = 0.f; }
    __syncthreads();

    int nb = min(bCnt[blockIdx.x * 16], cap);
    const uint2* buf = bbuf + (size_t)blockIdx.x * cap;
    for (int i = tid; i < nb; i += 256) {
        uint2 u = buf[i];
        int local = (int)u.x - base;
        int pos = atomicAdd(&cntL[local], 1);
        atomicAdd(&wsumL[local], (float)(u.y & 32767u) * WINV);
        if (pos < SLOTS) {
            slotsL[local * 32 + pos] = u.y;
        } else {
            int o = atomicAdd(ovCnt, 1);
            if (o < OV_CAP) ov[o] = u;
        }
    }
    // bucket-overflow edges from phase A (rare): fold into this range's structure
    int no = min(*ovACnt, OVA_CAP);
    for (int k = tid; k < no; k += 256) {
        uint2 u = ovA[k];
        int local = (int)u.x - base;
        if (local >= 0 && local < RNODES) {
            int pos = atomicAdd(&cntL[local], 1);
            atomicAdd(&wsumL[local], (float)(u.y & 32767u) * WINV);
            if (pos < SLOTS) {
                slotsL[local * 32 + pos] = u.y;
            } else {
                int o = atomicAdd(ovCnt, 1);
                if (o < OV_CAP) ov[o] = u;
            }
        }
    }
    __syncthreads();

    // pad slots to mult-of-8 with (self, w=0); cnt; dinv = rsqrt(1 + sum w)
    for (int j = tid; j < RNODES; j += 256) {
        int node = base + j;
        if (node < n) {
            int c = cntL[j];
            int cm = min(c, SLOTS);
            int c8 = (cm + 7) & ~7;
            for (int k2 = cm; k2 < c8; ++k2) slotsL[j * 32 + k2] = (unsigned)node << 15;
            cnt[node] = c;
            dinv[node] = rsqrtf(fmaxf(1.f + wsumL[j], 1e-12f));
        }
    }
    __syncthreads();

    int vnodes = min(n - base, RNODES);
    if (vnodes <= 0) return;
    const uint4* sl4 = (const uint4*)slotsL;
    uint4* sg4 = (uint4*)(slots + ((size_t)base << 5));
    int lim = vnodes * 8;                      // uint4s = nodes*32/4
    for (int i = tid; i < lim; i += 256) sg4[i] = sl4[i];
}

// ---------------- fused preprocess (gemm0+gemm1): h=relu(bn(x@Wpre+b)); h0=h; ts8=fp8(dinv*(h@W1))
// LDS union tile: B_pre -> h-tile -> B_W1. Kills gemm1's 25.6MB h0 re-read + one launch.
// Pure GEMM->GEMM fusion (barrier-tolerant); the round-5 regression was agg-in-kernel, not this.
// B staged col-permuted: lane m holds actual cols m*8..m*8+7 -> bf16x8 vector stores.

__device__ __forceinline__ void stageB512(const bf16_t* __restrict__ WT, bf16_t* __restrict__ Bs,
                                          int tid) {
    const uint4* src = (const uint4*)WT;
    uint4* dst = (uint4*)Bs;
    for (int i = tid; i < 128 * 17; i += 512) {
        int row = i / 17, k = i - row * 17;
        int so = ((row & 15) << 3) | (row >> 4);
        dst[row * 17 + k] = src[so * 17 + k];
    }
}

__device__ __forceinline__ void mfma128(const bf16_t* __restrict__ Bs, const bf16x8* af,
                                        f32x4* acc, int m, int q) {
#pragma unroll
    for (int kk = 0; kk < 4; ++kk) {
#pragma unroll
        for (int c = 0; c < 8; ++c) {
            bf16x8 bfr = *(const bf16x8*)&Bs[(c * 16 + m) * 136 + q * 8 + kk * 32];
            acc[c] = __builtin_amdgcn_mfma_f32_16x16x32_bf16(af[kk], bfr, acc[c], 0, 0, 0);
        }
    }
}

__global__ __launch_bounds__(512) void fusePreK(
    const float* __restrict__ x, const bf16_t* __restrict__ WTpre, const bf16_t* __restrict__ WT1,
    bf16_t* __restrict__ h0, unsigned* __restrict__ ts8,
    const float* __restrict__ b_pre,
    const float* __restrict__ bnMean, const float* __restrict__ bnVar,
    const float* __restrict__ bnG, const float* __restrict__ bnB,
    const float* __restrict__ dinv, int n)
{
    __shared__ __align__(16) bf16_t U[128 * 136];   // union: B-tile / h-tile
    int tid = threadIdx.x;
    int rb = blockIdx.x * 128;
    int lane = tid & 63, wid = tid >> 6;
    int m = lane & 15, q = lane >> 4;

    stageB512(WTpre, U, tid);

    float scale[8], shift[8];
#pragma unroll
    for (int c = 0; c < 8; ++c) {
        int j = m * 8 + c;                       // actual col under permuted B
        float rs = rsqrtf(bnVar[j] + EPS_BN);
        scale[c] = bnG[j] * rs;
        shift[c] = bnB[j] - bnMean[j] * scale[c] + b_pre[j] * scale[c];
    }

    int rowL = min(rb + wid * 16 + m, n - 1);
    bf16x8 af[4];
#pragma unroll
    for (int kk = 0; kk < 4; ++kk) {
        float4 v0 = ((const float4*)x)[rowL * 32 + q * 2 + kk * 8];
        float4 v1 = ((const float4*)x)[rowL * 32 + q * 2 + kk * 8 + 1];
        bf16x8 w8;
        w8[0] = (bf16_t)v0.x; w8[1] = (bf16_t)v0.y; w8[2] = (bf16_t)v0.z; w8[3] = (bf16_t)v0.w;
        w8[4] = (bf16_t)v1.x; w8[5] = (bf16_t)v1.y; w8[6] = (bf16_t)v1.z; w8[7] = (bf16_t)v1.w;
        af[kk] = w8;
    }
    __syncthreads();                             // B_pre staged

    f32x4 acc[8];
#pragma unroll
    for (int c = 0; c < 8; ++c) acc[c] = (f32x4){0.f, 0.f, 0.f, 0.f};
    mfma128(U, af, acc, m, q);
    __syncthreads();                             // all waves done reading B_pre

    int r0 = rb + wid * 16 + q * 4;
#pragma unroll
    for (int i = 0; i < 4; ++i) {
        bf16x8 hv;
#pragma unroll
        for (int c = 0; c < 8; ++c)
            hv[c] = (bf16_t)fmaxf(acc[c][i] * scale[c] + shift[c], 0.f);
        int lr = wid * 16 + q * 4 + i;
        *(uint4*)&U[lr * 136 + m * 8] = *(uint4*)&hv;
        int r = r0 + i;
        if (r < n) ((uint4*)h0)[r * 16 + m] = *(uint4*)&hv;
    }
    __syncthreads();                             // h-tile complete

    int lrow = min(wid * 16 + m, 127);
#pragma unroll
    for (int kk = 0; kk < 4; ++kk)
        af[kk] = *(const bf16x8*)&U[lrow * 136 + q * 8 + kk * 32];
    __syncthreads();                             // h-tile consumed
    stageB512(WT1, U, tid);
    __syncthreads();

#pragma unroll
    for (int c = 0; c < 8; ++c) acc[c] = (f32x4){0.f, 0.f, 0.f, 0.f};
    mfma128(U, af, acc, m, q);

    float dv[4];
#pragma unroll
    for (int i = 0; i < 4; ++i) dv[i] = (r0 + i < n) ? dinv[r0 + i] : 0.f;
#pragma unroll
    for (int i = 0; i < 4; ++i) {
        int r = r0 + i;
        if (r < n) {
            float v0 = acc[0][i] * dv[i], v1 = acc[1][i] * dv[i];
            float v2 = acc[2][i] * dv[i], v3 = acc[3][i] * dv[i];
            float v4 = acc[4][i] * dv[i], v5 = acc[5][i] * dv[i];
            float v6 = acc[6][i] * dv[i], v7 = acc[7][i] * dv[i];
            int lo = __builtin_amdgcn_cvt_pk_fp8_f32(v0, v1, 0, false);
            lo = __builtin_amdgcn_cvt_pk_fp8_f32(v2, v3, lo, true);
            int hi = __builtin_amdgcn_cvt_pk_fp8_f32(v4, v5, 0, false);
            hi = __builtin_amdgcn_cvt_pk_fp8_f32(v6, v7, hi, true);
            ((uint2*)ts8)[(r << 4) | m] = make_uint2((unsigned)lo, (unsigned)hi);
        }
    }
}

// ---------------- GEMM (conv2): ts8 = fp8(dinv * (bufB@W2)), round-2 proven form ---------------

template <int MODE, typename AT>
__global__ __launch_bounds__(256) void gemm128K(
    const AT* __restrict__ A, const bf16_t* __restrict__ WT,
    bf16_t* __restrict__ outb, unsigned* __restrict__ out8,
    const float* __restrict__ dinv, int nrows)
{
    __shared__ __align__(16) bf16_t Bs[128 * 136];   // 34816 B
    int tid = threadIdx.x;
    int rb = blockIdx.x * 64;

    {
        const uint4* src = (const uint4*)WT;
        uint4* dst = (uint4*)Bs;
        for (int i = tid; i < 128 * 17; i += 256) {
            int row = i / 17, k = i - row * 17;
            int so = ((row & 15) << 3) | (row >> 4);
            dst[row * 17 + k] = src[so * 17 + k];
        }
    }

    int lane = tid & 63;
    int wid = tid >> 6;
    int m = lane & 15, q = lane >> 4;
    int rowL = min(rb + wid * 16 + m, nrows - 1);

    bf16x8 af[4];
#pragma unroll
    for (int kk = 0; kk < 4; ++kk)
        af[kk] = ((const bf16x8*)A)[rowL * 16 + q + kk * 4];

    __syncthreads();

    f32x4 acc[8];
#pragma unroll
    for (int c = 0; c < 8; ++c) acc[c] = (f32x4){0.f, 0.f, 0.f, 0.f};

#pragma unroll
    for (int kk = 0; kk < 4; ++kk) {
#pragma unroll
        for (int c = 0; c < 8; ++c) {
            bf16x8 bfr = *(const bf16x8*)&Bs[(c * 16 + m) * 136 + q * 8 + kk * 32];
            acc[c] = __builtin_amdgcn_mfma_f32_16x16x32_bf16(af[kk], bfr, acc[c], 0, 0, 0);
        }
    }

    int r0 = rb + wid * 16 + q * 4;
    float dv[4];
#pragma unroll
    for (int i = 0; i < 4; ++i) dv[i] = (r0 + i < nrows) ? dinv[r0 + i] : 0.f;
#pragma unroll
    for (int i = 0; i < 4; ++i) {
        int r = r0 + i;
        if (r < nrows) {
            float v0 = acc[0][i] * dv[i], v1 = acc[1][i] * dv[i];
            float v2 = acc[2][i] * dv[i], v3 = acc[3][i] * dv[i];
            float v4 = acc[4][i] * dv[i], v5 = acc[5][i] * dv[i];
            float v6 = acc[6][i] * dv[i], v7 = acc[7][i] * dv[i];
            int lo = __builtin_amdgcn_cvt_pk_fp8_f32(v0, v1, 0, false);
            lo = __builtin_amdgcn_cvt_pk_fp8_f32(v2, v3, lo, true);
            int hi = __builtin_amdgcn_cvt_pk_fp8_f32(v4, v5, 0, false);
            hi = __builtin_amdgcn_cvt_pk_fp8_f32(v6, v7, hi, true);
            ((uint2*)out8)[(r << 4) | m] = make_uint2((unsigned)lo, (unsigned)hi);
        }
    }
}

// ---------------- aggregation (half-wave per node, wide fp8 gather, branchless) ----------------
// Round-2 proven form. FETCH = 8 XCDs x 12.8MB table is structural for a uniform-random
// graph (R7/R8 partitioning attempts both regressed: dispatch->XCD affinity doesn't hold).

template <int RELU, int RES>
__global__ __launch_bounds__(256) void aggK(
    const uint4* __restrict__ ts16, const unsigned* __restrict__ slots,
    const int* __restrict__ cnt, const float* __restrict__ dinv,
    const float4* __restrict__ bias, const uint4* __restrict__ residual,
    uint4* __restrict__ out,
    const uint2* __restrict__ ov, const int* __restrict__ ovCnt, int n)
{
    int tid = threadIdx.x;
    int node = blockIdx.x * 8 + (tid >> 5);
    int hl = tid & 31;
    int hb = tid & 32;
    if (node >= n) return;
    int slot = hl >> 3;
    int f = hl & 7;
    int nb = node << 5;

    int c8 = (min(cnt[node], SLOTS) + 7) & ~7;
    unsigned my = slots[nb | hl];
    float myw = (float)(my & 32767u) * WINV;
    int myoff = (int)(my >> 15) << 3;     // uint4 units: src*8

    f32x2 acc[8];
#pragma unroll
    for (int k = 0; k < 8; ++k) acc[k] = (f32x2){0.f, 0.f};

    // self-loop row folded into slot-1 lanes (weight 1), overlaps the gather loop
    if (slot == 1) {
        uint4 su = ts16[(node << 3) + f];
        acc[0] += f8lo(su.x); acc[1] += f8hi(su.x);
        acc[2] += f8lo(su.y); acc[3] += f8hi(su.y);
        acc[4] += f8lo(su.z); acc[5] += f8hi(su.z);
        acc[6] += f8lo(su.w); acc[7] += f8hi(su.w);
    }

    for (int j = 0; j < c8; j += 8) {
        int s0 = hb + j + slot;
        int s1 = s0 + 4;
        int o0 = __shfl(myoff, s0);
        int o1 = __shfl(myoff, s1);
        float w0 = __shfl(myw, s0);
        float w1 = __shfl(myw, s1);
        uint4 u0 = ts16[o0 + f];
        uint4 u1 = ts16[o1 + f];
        ACC8(u0, w0);
        ACC8(u1, w1);
    }

    // overflow edges (rare): slot-0 lanes only, so reduction counts them once
    int no = min(*ovCnt, OV_CAP);
    for (int k = 0; k < no; ++k) {
        uint2 o = ov[k];
        if ((int)o.x == node && slot == 0) {
            uint4 u = ts16[((int)(o.y >> 15) << 3) + f];
            float w = (float)(o.y & 32767u) * WINV;
            ACC8(u, w);
        }
    }

    // reduce across the 4 edge slots (lanes hl^8, hl^16)
#pragma unroll
    for (int k = 0; k < 8; ++k) {
        f32x2 t;
        t.x = __shfl_xor(acc[k].x, 8);  t.y = __shfl_xor(acc[k].y, 8);
        acc[k] += t;
        t.x = __shfl_xor(acc[k].x, 16); t.y = __shfl_xor(acc[k].y, 16);
        acc[k] += t;
    }

    if (slot == 0) {   // lanes hl<8 hold chunk f; epilogue + write
        float di = dinv[node];
        float r[16];
#pragma unroll
        for (int k = 0; k < 8; ++k) {
            float4 bb = bias[f * 4 + (k >> 1)];
            float b0 = (k & 1) ? bb.z : bb.x;
            float b1 = (k & 1) ? bb.w : bb.y;
            r[2 * k]     = acc[k].x * di + b0;
            r[2 * k + 1] = acc[k].y * di + b1;
        }
        if (RES) {
            uint4 q0 = residual[(node << 4) + f * 2];
            uint4 q1 = residual[(node << 4) + f * 2 + 1];
            r[0] += blo(q0.x);  r[1] += bhi(q0.x);
            r[2] += blo(q0.y);  r[3] += bhi(q0.y);
            r[4] += blo(q0.z);  r[5] += bhi(q0.z);
            r[6] += blo(q0.w);  r[7] += bhi(q0.w);
            r[8] += blo(q1.x);  r[9] += bhi(q1.x);
            r[10] += blo(q1.y); r[11] += bhi(q1.y);
            r[12] += blo(q1.z); r[13] += bhi(q1.z);
            r[14] += blo(q1.w); r[15] += bhi(q1.w);
        }
        if (RELU) {
#pragma unroll
            for (int k = 0; k < 16; ++k) r[k] = fmaxf(r[k], 0.f);
        }
        bf16x8 o0, o1;
#pragma unroll
        for (int k = 0; k < 8; ++k) { o0[k] = (bf16_t)r[k]; o1[k] = (bf16_t)r[8 + k]; }
        out[(node << 4) + f * 2]     = *(uint4*)&o0;
        out[(node << 4) + f * 2 + 1] = *(uint4*)&o1;
    }
}

// ---------------- classifier: z = h@Wc1 + bc1; LN; ReLU; out = z@Wc2 + bc2 ----------------

__global__ __launch_bounds__(256) void classifierK(
    const bf16_t* __restrict__ A, const bf16_t* __restrict__ WT,
    const float* __restrict__ bc1, const float* __restrict__ g,
    const float* __restrict__ b, const float* __restrict__ Wc2,
    const float* __restrict__ bc2, float* __restrict__ out, int nrows)
{
    __shared__ __align__(16) bf16_t Bs[128 * 136];
    __shared__ float sB[128], sG[128], sLb[128], sW2[384];
    int tid = threadIdx.x;
    int rb = blockIdx.x * 64;

    {
        const uint4* src = (const uint4*)WT;
        uint4* dst = (uint4*)Bs;
        for (int i = tid; i < 128 * 17; i += 256) dst[i] = src[i];
    }
    if (tid < 128) { sB[tid] = bc1[tid]; sG[tid] = g[tid]; sLb[tid] = b[tid]; }
    for (int i = tid; i < 384; i += 256) sW2[i] = Wc2[i];

    int lane = tid & 63;
    int wid = tid >> 6;
    int m = lane & 15, q = lane >> 4;
    int rowL = min(rb + wid * 16 + m, nrows - 1);

    bf16x8 af[4];
#pragma unroll
    for (int kk = 0; kk < 4; ++kk)
        af[kk] = ((const bf16x8*)A)[rowL * 16 + q + kk * 4];

    __syncthreads();

    f32x4 acc[8];
#pragma unroll
    for (int c = 0; c < 8; ++c) acc[c] = (f32x4){0.f, 0.f, 0.f, 0.f};
#pragma unroll
    for (int kk = 0; kk < 4; ++kk) {
#pragma unroll
        for (int c = 0; c < 8; ++c) {
            bf16x8 bfr = *(const bf16x8*)&Bs[(c * 16 + m) * 136 + q * 8 + kk * 32];
            acc[c] = __builtin_amdgcn_mfma_f32_16x16x32_bf16(af[kk], bfr, acc[c], 0, 0, 0);
        }
    }

    int r0 = rb + wid * 16 + q * 4;
#pragma unroll
    for (int i = 0; i < 4; ++i) {
        float s1 = 0.f, s2 = 0.f;
#pragma unroll
        for (int c = 0; c < 8; ++c) {
            float z = acc[c][i] + sB[c * 16 + m];
            acc[c][i] = z;
            s1 += z; s2 += z * z;
        }
#pragma unroll
        for (int off = 1; off < 16; off <<= 1) {
            s1 += __shfl_xor(s1, off);
            s2 += __shfl_xor(s2, off);
        }
        float mu = s1 * (1.f / 128.f);
        float var = s2 * (1.f / 128.f) - mu * mu;
        float rstd = rsqrtf(var + EPS_LN);
        float p0 = 0.f, p1 = 0.f, p2 = 0.f;
#pragma unroll
        for (int c = 0; c < 8; ++c) {
            int j = c * 16 + m;
            float zn = (acc[c][i] - mu) * rstd * sG[j] + sLb[j];
            zn = fmaxf(zn, 0.f);
            p0 += zn * sW2[j * 3 + 0];
            p1 += zn * sW2[j * 3 + 1];
            p2 += zn * sW2[j * 3 + 2];
        }
#pragma unroll
        for (int off = 1; off < 16; off <<= 1) {
            p0 += __shfl_xor(p0, off);
            p1 += __shfl_xor(p1, off);
            p2 += __shfl_xor(p2, off);
        }
        int r = r0 + i;
        if (m == 0 && r < nrows) {
            out[r * 3 + 0] = p0 + bc2[0];
            out[r * 3 + 1] = p1 + bc2[1];
            out[r * 3 + 2] = p2 + bc2[2];
        }
    }
}

// ---------------- launch ----------------

extern "C" void kernel_launch(void* const* d_in, const int* in_sizes, int n_in,
                              void* d_out, int out_size, void* d_ws, size_t ws_size,
                              hipStream_t stream) {
    const float* x      = (const float*)d_in[0];
    const int*   ei     = (const int*)d_in[1];
    const float* ea     = (const float*)d_in[2];
    const float* W_pre  = (const float*)d_in[3];
    const float* b_pre  = (const float*)d_in[4];
    const float* bn_g   = (const float*)d_in[5];
    const float* bn_b   = (const float*)d_in[6];
    const float* bn_m   = (const float*)d_in[7];
    const float* bn_v   = (const float*)d_in[8];
    const float* W1     = (const float*)d_in[9];
    const float* b1     = (const float*)d_in[10];
    const float* W2     = (const float*)d_in[11];
    const float* b2     = (const float*)d_in[12];
    const float* Wc1    = (const float*)d_in[13];
    const float* bc1    = (const float*)d_in[14];
    const float* ln_g   = (const float*)d_in[15];
    const float* ln_b   = (const float*)d_in[16];
    const float* Wc2    = (const float*)d_in[17];
    const float* bc2    = (const float*)d_in[18];
    float* outp = (float*)d_out;

    const int N = in_sizes[0] / 128;
    const int E = in_sizes[2];

    char* p = (char*)d_ws;
    auto alloc = [&](size_t bytes) -> void* {
        void* r = (void*)p;
        p += (bytes + 255) & ~(size_t)255;
        return r;
    };
    bf16_t*   h0    = (bf16_t*)alloc((size_t)N * 128 * 2);
    bf16_t*   bufB  = (bf16_t*)alloc((size_t)N * 128 * 2);
    unsigned* ts8   = (unsigned*)alloc((size_t)N * 128);
    float*    dinv  = (float*)alloc((size_t)N * 4);
    int*      cnt   = (int*)alloc((size_t)N * 4);
    int*      ovCnt = (int*)alloc(256);
    int*      ovACnt= (int*)alloc(256);
    uint2*    ov    = (uint2*)alloc((size_t)OV_CAP * 8);
    uint2*    ovA   = (uint2*)alloc((size_t)OVA_CAP * 8);
    unsigned* slots = (unsigned*)alloc((size_t)N * SLOTS * 4);
    bf16_t*   WT    = (bf16_t*)alloc((size_t)4 * 128 * 136 * 2);
    int       nbuck = (N + RNODES - 1) / RNODES;      // 224 for N=100000
    int       cap   = E / nbuck + 4096;
    uint2*    bbuf  = (uint2*)alloc((size_t)nbuck * cap * 8);
    int*      bCnt  = (int*)alloc(4096 * 4);

    bf16_t* WT_pre = WT + 0 * 128 * 136;
    bf16_t* WT_1   = WT + 1 * 128 * 136;
    bf16_t* WT_2   = WT + 2 * 128 * 136;
    bf16_t* WT_c1  = WT + 3 * 128 * 136;

    int gG = (N + 63) / 64;
    int gF = (N + 127) / 128;
    int gH = (N + 7) / 8;
    int gP = 65536 / 256;
    int gBin = (E + 4095) / 4096;

    prepK<<<gP, 256, 0, stream>>>(W_pre, W1, W2, Wc1, WT, bCnt, ovCnt, ovACnt);
    binK<<<gBin, 256, 0, stream>>>(ei, ea, bbuf, bCnt, ovA, ovACnt, E, cap, nbuck);
    buildK<<<nbuck, 256, 0, stream>>>(bbuf, bCnt, ovA, ovACnt, slots, cnt, dinv, ov, ovCnt, cap, N);

    // fused: h0 = relu(bn(x@W_pre + b_pre)); ts8 = fp8(dinv * (h0@W1))
    fusePreK<<<gF, 512, 0, stream>>>(x, WT_pre, WT_1, h0, ts8, b_pre, bn_m, bn_v, bn_g, bn_b, dinv, N);
    // conv1 aggregation
    aggK<1, 0><<<gH, 256, 0, stream>>>((const uint4*)ts8, slots, cnt, dinv, (const float4*)b1,
                                       nullptr, (uint4*)bufB, ov, ovCnt, N);
    // conv2 gemm
    gemm128K<1, bf16_t><<<gG, 256, 0, stream>>>(bufB, WT_2, nullptr, ts8, dinv, N);
    // conv2 aggregation (+residual h0)
    aggK<0, 1><<<gH, 256, 0, stream>>>((const uint4*)ts8, slots, cnt, dinv, (const float4*)b2,
                                       (const uint4*)h0, (uint4*)bufB, ov, ovCnt, N);
    // classifier: out = relu(LN(h@Wc1 + bc1)) @ Wc2 + bc2
    classifierK<<<gG, 256, 0, stream>>>(bufB, WT_c1, bc1, ln_g, ln_b, Wc2, bc2, outp, N);
}